// Round 2
// baseline (325.633 us; speedup 1.0000x reference)
//
#include <hip/hip_runtime.h>
#include <stdint.h>

#define FEAT 32

// ---------------------------------------------------------------------------
// CSR-build + gather-reduce segment_sum:
//   out[n][f] = sum over edges e with dst[e]==n of x[src[e]][f] * w[e]
// Replaces 64M fp32 device-scope atomics (256 MB write-through, the round-1
// bottleneck) with 4M int atomics + a gather that writes out exactly once.
// ---------------------------------------------------------------------------

// Phase 1: degree histogram of dst
__global__ void k_hist(const int* __restrict__ ei, int* __restrict__ deg, int E) {
    int e = blockIdx.x * blockDim.x + threadIdx.x;
    if (e >= E) return;
    atomicAdd(&deg[ei[E + e]], 1);
}

// Phase 2a: per-block (256-wide) sums of deg
__global__ void k_partial_sum(const int* __restrict__ deg, int* __restrict__ partial, int N) {
    __shared__ int s[256];
    int i = blockIdx.x * 256 + threadIdx.x;
    s[threadIdx.x] = (i < N) ? deg[i] : 0;
    __syncthreads();
    for (int off = 128; off > 0; off >>= 1) {
        if (threadIdx.x < off) s[threadIdx.x] += s[threadIdx.x + off];
        __syncthreads();
    }
    if (threadIdx.x == 0) partial[blockIdx.x] = s[0];
}

// Phase 2b: exclusive scan of partials in place (single block, P <= 1024)
__global__ void k_scan_partials(int* __restrict__ partial, int P) {
    __shared__ int s[1024];
    int t = threadIdx.x;
    s[t] = (t < P) ? partial[t] : 0;
    __syncthreads();
    for (int off = 1; off < 1024; off <<= 1) {
        int v = (t >= off) ? s[t - off] : 0;
        __syncthreads();
        s[t] += v;
        __syncthreads();
    }
    if (t < P) partial[t] = (t == 0) ? 0 : s[t - 1];
    // s holds inclusive scan; exclusive[t] = inclusive[t-1]
}

// Phase 2c: block-local exclusive scan + partial offset -> off, cursor
__global__ void k_scan_final(const int* __restrict__ deg, const int* __restrict__ partial,
                             int* __restrict__ off, int* __restrict__ cur, int N) {
    __shared__ int s[256];
    int t = threadIdx.x;
    int i = blockIdx.x * 256 + t;
    int v = (i < N) ? deg[i] : 0;
    s[t] = v;
    __syncthreads();
    for (int o = 1; o < 256; o <<= 1) {
        int u = (t >= o) ? s[t - o] : 0;
        __syncthreads();
        s[t] += u;
        __syncthreads();
    }
    if (i < N) {
        int excl = partial[blockIdx.x] + s[t] - v;  // inclusive - self
        off[i] = excl;
        cur[i] = excl;
    }
}

// Phase 3: scatter (src, w) packed into CSR slots
__global__ void k_scatter(const int* __restrict__ ei, const float* __restrict__ ew,
                          int* __restrict__ cur, uint64_t* __restrict__ packed, int E) {
    int e = blockIdx.x * blockDim.x + threadIdx.x;
    if (e >= E) return;
    int src = ei[e];
    int dst = ei[E + e];
    uint32_t wbits = __float_as_uint(ew[e]);
    int pos = atomicAdd(&cur[dst], 1);
    packed[pos] = ((uint64_t)wbits << 32) | (uint32_t)src;
}

// Phase 4: gather-reduce. Half-wave (32 lanes = 32 features) per node.
// Edge list loaded cooperatively (coalesced) in batches of 32, broadcast
// via __shfl within the 32-lane group.
__global__ void k_gather(const float* __restrict__ x, const int* __restrict__ off,
                         const int* __restrict__ deg, const uint64_t* __restrict__ packed,
                         float* __restrict__ out, int N) {
    int tid = blockIdx.x * blockDim.x + threadIdx.x;
    int node = tid >> 5;
    if (node >= N) return;
    int f = tid & 31;
    int start = off[node];
    int d = deg[node];
    float acc = 0.0f;
    for (int base = 0; base < d; base += 32) {
        int m = min(32, d - base);
        unsigned long long mine = 0;
        if (f < m) mine = packed[start + base + f];   // coalesced 256B per half-wave
        for (int j = 0; j < m; ++j) {
            unsigned long long p = __shfl(mine, j, 32);
            int src = (int)(uint32_t)p;
            float w = __uint_as_float((uint32_t)(p >> 32));
            acc = fmaf(x[(long long)src * FEAT + f], w, acc);  // coalesced 128B gather
        }
    }
    out[(long long)node * FEAT + f] = acc;  // every out element written exactly once
}

// Fallback (round-1): direct scatter-add, used only if ws_size is too small.
__global__ void k_atomic_fallback(const float* __restrict__ x, const int* __restrict__ ei,
                                  const float* __restrict__ ew, float* __restrict__ out, int E) {
    int tid = blockIdx.x * blockDim.x + threadIdx.x;
    int e = tid >> 5;
    if (e >= E) return;
    int f = tid & 31;
    float v = x[(long long)ei[e] * FEAT + f] * ew[e];
    unsafeAtomicAdd(&out[(long long)ei[E + e] * FEAT + f], v);
}

extern "C" void kernel_launch(void* const* d_in, const int* in_sizes, int n_in,
                              void* d_out, int out_size, void* d_ws, size_t ws_size,
                              hipStream_t stream) {
    const float* x  = (const float*)d_in[0];
    const int*   ei = (const int*)d_in[1];
    const float* ew = (const float*)d_in[2];
    float* out = (float*)d_out;

    const int E = in_sizes[2];
    const int N = in_sizes[0] / FEAT;
    const int P = (N + 255) / 256;   // number of scan partials

    // ws layout: deg[N] | off[N] | cur[N] | partial[P] | packed[E] (8B aligned)
    int* deg = (int*)d_ws;
    int* off = deg + N;
    int* cur = off + N;
    int* partial = cur + N;
    uint64_t* packed = (uint64_t*)(((uintptr_t)(partial + P) + 15) & ~(uintptr_t)15);
    size_t need = (size_t)((char*)(packed + E) - (char*)d_ws);

    if (ws_size < need || P > 1024) {
        // Not enough scratch: fall back to the atomic version.
        hipMemsetAsync(d_out, 0, (size_t)out_size * sizeof(float), stream);
        long long total = (long long)E * FEAT;
        k_atomic_fallback<<<(int)((total + 255) / 256), 256, 0, stream>>>(x, ei, ew, out, E);
        return;
    }

    hipMemsetAsync(deg, 0, (size_t)N * sizeof(int), stream);

    k_hist<<<(E + 255) / 256, 256, 0, stream>>>(ei, deg, E);
    k_partial_sum<<<P, 256, 0, stream>>>(deg, partial, N);
    k_scan_partials<<<1, 1024, 0, stream>>>(partial, P);
    k_scan_final<<<P, 256, 0, stream>>>(deg, partial, off, cur, N);
    k_scatter<<<(E + 255) / 256, 256, 0, stream>>>(ei, ew, cur, packed, E);

    long long gthreads = (long long)N * FEAT;
    k_gather<<<(int)((gthreads + 255) / 256), 256, 0, stream>>>(x, off, deg, packed, out, N);
}